// Round 1
// baseline (430.848 us; speedup 1.0000x reference)
//
#include <hip/hip_runtime.h>

typedef __bf16 b16x8 __attribute__((ext_vector_type(8)));
typedef float  f32x4 __attribute__((ext_vector_type(4)));
typedef unsigned short u16;

#define BN_TOT 1200
#define NCOL   53248   // G*(PW+SP) = 4*13312
#define QD     256

__device__ __forceinline__ u16 f2bf(float f) {
  union { float f; unsigned u; } v; v.f = f;
  unsigned r = v.u + 0x7FFFu + ((v.u >> 16) & 1u);   // RNE
  return (u16)(r >> 16);
}

// ---------------------------------------------------------------------------
// K0: W_v (8192x256 f32, row-major) -> W_vT (256x8192 bf16), tiled transpose
// ---------------------------------------------------------------------------
__global__ __launch_bounds__(256) void k_twv(const float* __restrict__ Wv,
                                             u16* __restrict__ WvT) {
  __shared__ float t[64][65];
  const int kb = blockIdx.x * 64, cb = blockIdx.y * 64;
  const int tid = threadIdx.x;
  for (int i = 0; i < 16; ++i) {
    int idx = i * 256 + tid;
    int kk = idx >> 6, cc = idx & 63;
    t[kk][cc] = Wv[(size_t)(kb + kk) * 256 + cb + cc];
  }
  __syncthreads();
  for (int i = 0; i < 16; ++i) {
    int idx = i * 256 + tid;
    int cc = idx >> 6, kk = idx & 63;
    WvT[(size_t)(cb + cc) * 8192 + kb + kk] = f2bf(t[kk][cc]);
  }
}

// ---------------------------------------------------------------------------
// K_mb: mb = query @ W_bias + b_bias   (1200 x 384, K=256), fp32 VALU
// ---------------------------------------------------------------------------
__global__ __launch_bounds__(384) void k_mb(const float* __restrict__ qry,
                                            const float* __restrict__ Wb,
                                            const float* __restrict__ bb,
                                            float* __restrict__ mbo) {
  const int j = threadIdx.x;          // 0..383
  const int bn0 = blockIdx.x * 8;     // 150 blocks
  float acc[8] = {0, 0, 0, 0, 0, 0, 0, 0};
  for (int q = 0; q < 256; ++q) {
    float w = Wb[(size_t)q * 384 + j];
#pragma unroll
    for (int i = 0; i < 8; ++i) acc[i] += qry[(size_t)(bn0 + i) * 256 + q] * w;
  }
  float b = bb[j];
#pragma unroll
  for (int i = 0; i < 8; ++i) mbo[(size_t)(bn0 + i) * 384 + j] = acc[i] + b;
}

// ---------------------------------------------------------------------------
// K1: params = bf16(query @ W_gen + b_gen)   (1200 x 53248, K=256)
// 416 blocks; each owns a 128-col slice of W_gen (read once, kept in LDS
// transposed) and loops all 19 row-chunks of 64 queries.
// ---------------------------------------------------------------------------
__global__ __launch_bounds__(256) void k_params(const float* __restrict__ qry,
                                                const float* __restrict__ Wg,
                                                const float* __restrict__ bg,
                                                u16* __restrict__ P) {
  __shared__ __align__(16) u16 lds[128 * 264 + 64 * 264];  // 101 KB
  u16* BtT = lds;               // [col 0..127][264], q-contiguous (528B stride)
  u16* At  = lds + 128 * 264;   // [row 0..63][264]
  u16* Ct  = At;                // reused for epilogue, stride 136 u16 (272B)

  const int tid  = threadIdx.x;
  const int col0 = blockIdx.x * 128;
  const int wave = tid >> 6, lane = tid & 63;
  const int l15  = lane & 15, lhi = lane >> 4;

  // load + transpose + bf16 the W_gen slice
  for (int i = 0; i < 32; ++i) {
    int idx4 = i * 256 + tid;           // 8192 float4 = 256x128
    int q = idx4 >> 5, j4 = idx4 & 31;
    float4 v = *(const float4*)&Wg[(size_t)q * NCOL + col0 + j4 * 4];
    int cb = j4 * 4;
    BtT[(cb + 0) * 264 + q] = f2bf(v.x);
    BtT[(cb + 1) * 264 + q] = f2bf(v.y);
    BtT[(cb + 2) * 264 + q] = f2bf(v.z);
    BtT[(cb + 3) * 264 + q] = f2bf(v.w);
  }
  __syncthreads();

  // hold B fragments across all row chunks: wave owns cols [wave*32, +32)
  b16x8 bfrag[2][8];
  for (int nt = 0; nt < 2; ++nt)
    for (int kk = 0; kk < 8; ++kk) {
      int col = wave * 32 + nt * 16 + l15;
      bfrag[nt][kk] = *(const b16x8*)&BtT[col * 264 + kk * 32 + lhi * 8];
    }
  float bcol[2];
  for (int nt = 0; nt < 2; ++nt)
    bcol[nt] = bg[col0 + wave * 32 + nt * 16 + l15];

  for (int rc = 0; rc < 19; ++rc) {
    int r0 = rc * 64;
    for (int i = 0; i < 16; ++i) {
      int idx4 = i * 256 + tid;          // 4096 float4 = 64x256
      int rr = idx4 >> 6, q4 = idx4 & 63;
      int row = r0 + rr;
      float4 v = make_float4(0.f, 0.f, 0.f, 0.f);
      if (row < BN_TOT) v = *(const float4*)&qry[(size_t)row * QD + q4 * 4];
      u16* d = &At[rr * 264 + q4 * 4];
      d[0] = f2bf(v.x); d[1] = f2bf(v.y); d[2] = f2bf(v.z); d[3] = f2bf(v.w);
    }
    __syncthreads();

    f32x4 acc[4][2] = {};
    for (int mt = 0; mt < 4; ++mt)
      for (int kk = 0; kk < 8; ++kk) {
        b16x8 af = *(const b16x8*)&At[(mt * 16 + l15) * 264 + kk * 32 + lhi * 8];
        acc[mt][0] = __builtin_amdgcn_mfma_f32_16x16x32_bf16(af, bfrag[0][kk], acc[mt][0], 0, 0, 0);
        acc[mt][1] = __builtin_amdgcn_mfma_f32_16x16x32_bf16(af, bfrag[1][kk], acc[mt][1], 0, 0, 0);
      }
    __syncthreads();  // done reading At

    for (int mt = 0; mt < 4; ++mt)
      for (int nt = 0; nt < 2; ++nt) {
        int col_l = wave * 32 + nt * 16 + l15;
        for (int r = 0; r < 4; ++r) {
          int row_l = mt * 16 + lhi * 4 + r;
          Ct[row_l * 136 + col_l] = f2bf(acc[mt][nt][r] + bcol[nt]);
        }
      }
    __syncthreads();

    for (int i = 0; i < 4; ++i) {
      int chunk = i * 256 + tid;          // 1024 chunks of 16B
      int row_l = chunk >> 4, cr = chunk & 15;
      int grow = r0 + row_l;
      if (grow < BN_TOT)
        *(int4*)&P[(size_t)grow * NCOL + col0 + cr * 8] =
            *(const int4*)&Ct[row_l * 136 + cr * 8];
    }
    __syncthreads();  // Ct space becomes At next iteration
  }
}

// ---------------------------------------------------------------------------
// K2: per-(bn,g) cascade mix:
//   h1 = relu(x @ M / 8 + M_b);  h2 = relu(S @ h1 + S_b)  -> H[bn][o][g][c]
// ---------------------------------------------------------------------------
__global__ __launch_bounds__(256) void k_mix(const float* __restrict__ x,
                                             const u16* __restrict__ P,
                                             const float* __restrict__ mb,
                                             u16* __restrict__ H) {
  __shared__ __align__(16) u16 lds[64 * 72 + 32 * 296 + 288 * 72 + 64 * 296];
  u16* MtT = lds;                 // [d 0..63][72]  c-contig  (144B stride)
  u16* St  = lds + 64 * 72;       // [o 0..31][296] p-contig  (592B stride)
  u16* xt  = St + 32 * 296;       // [p 0..287][72] c-contig
  u16* h1T = xt + 288 * 72;       // [c 0..63][296] p-contig
  __shared__ float mbs[96];

  const int blk = blockIdx.x;
  const int bn = blk >> 2, g = blk & 3;
  const int tid = threadIdx.x;
  const int wave = tid >> 6, lane = tid & 63;
  const int l15 = lane & 15, lhi = lane >> 4;

  const size_t pb = (size_t)bn * NCOL + g * 13312;
  for (int i = 0; i < 4; ++i) {                      // M: 4096, transpose
    int idx4 = i * 256 + tid;
    int c = idx4 >> 4, d4 = (idx4 & 15) * 4;
    ushort4 v = *(const ushort4*)&P[pb + c * 64 + d4];
    MtT[(d4 + 0) * 72 + c] = v.x;
    MtT[(d4 + 1) * 72 + c] = v.y;
    MtT[(d4 + 2) * 72 + c] = v.z;
    MtT[(d4 + 3) * 72 + c] = v.w;
  }
  for (int i = 0; i < 9; ++i) {                      // S: 9216, direct
    int idx4 = i * 256 + tid;
    int o = idx4 / 72, p4 = (idx4 - o * 72) * 4;
    *(ushort4*)&St[o * 296 + p4] = *(const ushort4*)&P[pb + 4096 + (size_t)idx4 * 4];
  }
  const size_t xb = ((size_t)bn * 4 + g) * 18432;    // x: 18432 f32 -> bf16
  for (int i = 0; i < 18; ++i) {
    int idx4 = i * 256 + tid;
    int p = idx4 >> 4, c4 = (idx4 & 15) * 4;
    float4 v = *(const float4*)&x[xb + (size_t)idx4 * 4];
    u16* d = &xt[p * 72 + c4];
    d[0] = f2bf(v.x); d[1] = f2bf(v.y); d[2] = f2bf(v.z); d[3] = f2bf(v.w);
  }
  if (tid < 96) mbs[tid] = mb[(size_t)bn * 384 + g * 96 + tid];
  __syncthreads();

  // MFMA1: A=x (m=p), B=M (k=c, n=d), 18 m-tiles round-robin over 4 waves
  b16x8 mfrag[4][2];
  for (int nt = 0; nt < 4; ++nt)
    for (int kk = 0; kk < 2; ++kk)
      mfrag[nt][kk] = *(const b16x8*)&MtT[(nt * 16 + l15) * 72 + kk * 32 + lhi * 8];
  float mbv[4];
  for (int nt = 0; nt < 4; ++nt) mbv[nt] = mbs[nt * 16 + l15];

  for (int mt = wave; mt < 18; mt += 4) {
    f32x4 acc[4] = {};
    for (int kk = 0; kk < 2; ++kk) {
      b16x8 af = *(const b16x8*)&xt[(mt * 16 + l15) * 72 + kk * 32 + lhi * 8];
      for (int nt = 0; nt < 4; ++nt)
        acc[nt] = __builtin_amdgcn_mfma_f32_16x16x32_bf16(af, mfrag[nt][kk], acc[nt], 0, 0, 0);
    }
    for (int nt = 0; nt < 4; ++nt) {
      int d = nt * 16 + l15;
      for (int r = 0; r < 4; ++r) {
        float v = acc[nt][r] * 0.125f + mbv[nt];     // /TEMPER then +M_b
        h1T[d * 296 + mt * 16 + lhi * 4 + r] = f2bf(v > 0.f ? v : 0.f);
      }
    }
  }
  __syncthreads();

  // MFMA2: A=S (32x288), B=h1 (288x64), K=288 in 9 steps
  const int mt2 = wave >> 1;
  const int ntb = (wave & 1) * 2;
  f32x4 acc2[2] = {};
  for (int kk = 0; kk < 9; ++kk) {
    b16x8 af = *(const b16x8*)&St[(mt2 * 16 + l15) * 296 + kk * 32 + lhi * 8];
    for (int t = 0; t < 2; ++t) {
      b16x8 bf = *(const b16x8*)&h1T[((ntb + t) * 16 + l15) * 296 + kk * 32 + lhi * 8];
      acc2[t] = __builtin_amdgcn_mfma_f32_16x16x32_bf16(af, bf, acc2[t], 0, 0, 0);
    }
  }
  u16* Hp = H + (size_t)bn * 8192 + g * 64;          // H[bn][o][g][c]
  for (int t = 0; t < 2; ++t) {
    int c = (ntb + t) * 16 + l15;
    for (int r = 0; r < 4; ++r) {
      int o = mt2 * 16 + lhi * 4 + r;
      float v = acc2[t][r] + mbs[64 + o];
      Hp[o * 256 + c] = f2bf(v > 0.f ? v : 0.f);
    }
  }
}

// ---------------------------------------------------------------------------
// K3: partial[kz] = H[:, kz*1024:+1024] @ W_vT^T   (split-K=8, fp32 partials)
// ---------------------------------------------------------------------------
__global__ __launch_bounds__(256) void k_out(const u16* __restrict__ H,
                                             const u16* __restrict__ WvT,
                                             float* __restrict__ part) {
  __shared__ __align__(16) u16 lds[64 * 72 + 256 * 72];  // 46 KB
  u16* At  = lds;             // [row 0..63][72]
  u16* BtT = lds + 64 * 72;   // [col 0..255][72]

  const int tid = threadIdx.x;
  const int wave = tid >> 6, lane = tid & 63;
  const int l15 = lane & 15, lhi = lane >> 4;
  const int r0 = blockIdx.x * 64;
  const int k0 = blockIdx.y * 1024;

  f32x4 acc[4][4] = {};
  for (int it = 0; it < 16; ++it) {
    int kb = k0 + it * 64;
    for (int i = 0; i < 4; ++i) {
      int idx4 = i * 256 + tid;          // 1024 -> 64x64
      int rr = idx4 >> 4, q4 = (idx4 & 15) * 4;
      int row = r0 + rr;
      ushort4 v = make_ushort4(0, 0, 0, 0);
      if (row < BN_TOT) v = *(const ushort4*)&H[(size_t)row * 8192 + kb + q4];
      *(ushort4*)&At[rr * 72 + q4] = v;
    }
    for (int i = 0; i < 16; ++i) {
      int idx4 = i * 256 + tid;          // 4096 -> 256x64
      int col = idx4 >> 4, q4 = (idx4 & 15) * 4;
      *(ushort4*)&BtT[col * 72 + q4] = *(const ushort4*)&WvT[(size_t)col * 8192 + kb + q4];
    }
    __syncthreads();
    for (int kk = 0; kk < 2; ++kk) {
      b16x8 af[4], bf[4];
      for (int mt = 0; mt < 4; ++mt)
        af[mt] = *(const b16x8*)&At[(mt * 16 + l15) * 72 + kk * 32 + lhi * 8];
      for (int nt = 0; nt < 4; ++nt)
        bf[nt] = *(const b16x8*)&BtT[(wave * 64 + nt * 16 + l15) * 72 + kk * 32 + lhi * 8];
      for (int mt = 0; mt < 4; ++mt)
        for (int nt = 0; nt < 4; ++nt)
          acc[mt][nt] = __builtin_amdgcn_mfma_f32_16x16x32_bf16(af[mt], bf[nt], acc[mt][nt], 0, 0, 0);
    }
    __syncthreads();
  }
  const size_t pbase = (size_t)blockIdx.y * BN_TOT * 256;
  for (int mt = 0; mt < 4; ++mt)
    for (int nt = 0; nt < 4; ++nt) {
      int col = wave * 64 + nt * 16 + l15;
      for (int r = 0; r < 4; ++r) {
        int row = r0 + mt * 16 + lhi * 4 + r;
        if (row < BN_TOT) part[pbase + (size_t)row * 256 + col] = acc[mt][nt][r];
      }
    }
}

// ---------------------------------------------------------------------------
// K4: out = LayerNorm(sum_kz part + b_v) * ln_g + ln_b   (one block per row)
// ---------------------------------------------------------------------------
__global__ __launch_bounds__(256) void k_ln(const float* __restrict__ part,
                                            const float* __restrict__ bv,
                                            const float* __restrict__ lng,
                                            const float* __restrict__ lnb,
                                            float* __restrict__ out) {
  __shared__ float red[8];
  const int row = blockIdx.x, c = threadIdx.x;
  const int wave = c >> 6, lane = c & 63;
  float v = bv[c];
  for (int kz = 0; kz < 8; ++kz)
    v += part[((size_t)kz * BN_TOT + row) * 256 + c];
  float s = v;
  for (int off = 32; off > 0; off >>= 1) s += __shfl_xor(s, off);
  if (lane == 0) red[wave] = s;
  __syncthreads();
  float mean = (red[0] + red[1] + red[2] + red[3]) * (1.0f / 256.0f);
  float d = v - mean;
  float q = d * d;
  for (int off = 32; off > 0; off >>= 1) q += __shfl_xor(q, off);
  if (lane == 0) red[4 + wave] = q;
  __syncthreads();
  float var = (red[4] + red[5] + red[6] + red[7]) * (1.0f / 256.0f);
  out[(size_t)row * 256 + c] = d * rsqrtf(var + 1e-5f) * lng[c] + lnb[c];
}

// ---------------------------------------------------------------------------
extern "C" void kernel_launch(void* const* d_in, const int* in_sizes, int n_in,
                              void* d_out, int out_size, void* d_ws, size_t ws_size,
                              hipStream_t stream) {
  const float* x   = (const float*)d_in[0];
  const float* qry = (const float*)d_in[1];
  const float* Wg  = (const float*)d_in[2];
  const float* bg  = (const float*)d_in[3];
  const float* Wb  = (const float*)d_in[4];
  const float* bb  = (const float*)d_in[5];
  const float* Wv  = (const float*)d_in[6];
  const float* bv  = (const float*)d_in[7];
  const float* lng = (const float*)d_in[8];
  const float* lnb = (const float*)d_in[9];
  float* out = (float*)d_out;

  // ws layout (bytes), total 163,323,904:
  char* ws = (char*)d_ws;
  u16*   P    = (u16*)  (ws + 0);           // params bf16: 1200*53248*2
  u16*   H    = (u16*)  (ws + 127795200);   // h2 bf16:     1200*8192*2
  float* mbw  = (float*)(ws + 147456000);   // mix bias:    1200*384*4
  u16*   WvT  = (u16*)  (ws + 149299200);   // W_v^T bf16:  256*8192*2
  float* part = (float*)(ws + 153493504);   // splitK:      8*1200*256*4

  k_twv<<<dim3(128, 4), 256, 0, stream>>>(Wv, WvT);
  k_mb<<<150, 384, 0, stream>>>(qry, Wb, bb, mbw);
  k_params<<<416, 256, 0, stream>>>(qry, Wg, bg, P);
  k_mix<<<4800, 256, 0, stream>>>(x, P, mbw, H);
  k_out<<<dim3(19, 8), 256, 0, stream>>>(H, WvT, part);
  k_ln<<<1200, 256, 0, stream>>>(part, bv, lng, lnb, out);
}

// Round 2
// 390.322 us; speedup vs baseline: 1.1038x; 1.1038x over previous
//
#include <hip/hip_runtime.h>

typedef __bf16 bf16;
typedef __bf16 b16x8 __attribute__((ext_vector_type(8)));
typedef __bf16 b16x4 __attribute__((ext_vector_type(4)));
typedef float  f32x4 __attribute__((ext_vector_type(4)));
typedef float  f32x8 __attribute__((ext_vector_type(8)));

#define BN_TOT 1200
#define NCOL   53248   // G*(PW+SP) = 4*13312
#define QD     256

// ---------------------------------------------------------------------------
// K0: W_v (8192x256 f32, row-major) -> W_vT (256x8192 bf16), tiled transpose
// ---------------------------------------------------------------------------
__global__ __launch_bounds__(256) void k_twv(const float* __restrict__ Wv,
                                             bf16* __restrict__ WvT) {
  __shared__ float t[64][65];
  const int kb = blockIdx.x * 64, cb = blockIdx.y * 64;
  const int tid = threadIdx.x;
  for (int i = 0; i < 16; ++i) {
    int idx = i * 256 + tid;
    int kk = idx >> 6, cc = idx & 63;
    t[kk][cc] = Wv[(size_t)(kb + kk) * 256 + cb + cc];
  }
  __syncthreads();
  for (int i = 0; i < 16; ++i) {
    int idx = i * 256 + tid;
    int cc = idx >> 6, kk = idx & 63;
    WvT[(size_t)(cb + cc) * 8192 + kb + kk] = (bf16)t[kk][cc];
  }
}

// ---------------------------------------------------------------------------
// K_qbf: query f32 -> bf16, padded to 1216 rows (rows >=1200 zeroed) so
// k_params' A-fragment loads need no bounds checks.
// ---------------------------------------------------------------------------
__global__ __launch_bounds__(256) void k_qbf(const float* __restrict__ qry,
                                             bf16* __restrict__ qbf) {
  int gid = blockIdx.x * 256 + threadIdx.x;   // 152 blocks: 1216*256/8 threads
  int base = gid * 8;
  int row = base >> 8;
  b16x8 o;
#pragma unroll
  for (int i = 0; i < 8; ++i) o[i] = (bf16)0.f;
  if (row < BN_TOT) {
    float4 a0 = *(const float4*)&qry[base];
    float4 a1 = *(const float4*)&qry[base + 4];
    o[0] = (bf16)a0.x; o[1] = (bf16)a0.y; o[2] = (bf16)a0.z; o[3] = (bf16)a0.w;
    o[4] = (bf16)a1.x; o[5] = (bf16)a1.y; o[6] = (bf16)a1.z; o[7] = (bf16)a1.w;
  }
  *(b16x8*)&qbf[base] = o;
}

// ---------------------------------------------------------------------------
// K_mb: mb = query @ W_bias + b_bias   (1200 x 384, K=256), fp32 VALU
// ---------------------------------------------------------------------------
__global__ __launch_bounds__(384) void k_mb(const float* __restrict__ qry,
                                            const float* __restrict__ Wb,
                                            const float* __restrict__ bb,
                                            float* __restrict__ mbo) {
  const int j = threadIdx.x;          // 0..383
  const int bn0 = blockIdx.x * 8;     // 150 blocks
  float acc[8] = {0, 0, 0, 0, 0, 0, 0, 0};
  for (int q = 0; q < 256; ++q) {
    float w = Wb[(size_t)q * 384 + j];
#pragma unroll
    for (int i = 0; i < 8; ++i) acc[i] += qry[(size_t)(bn0 + i) * 256 + q] * w;
  }
  float b = bb[j];
#pragma unroll
  for (int i = 0; i < 8; ++i) mbo[(size_t)(bn0 + i) * 384 + j] = acc[i] + b;
}

// ---------------------------------------------------------------------------
// K1: P = bf16(query @ W_gen + b_gen)   (1200 x 53248, K=256)
// 416 blocks, each owns a 128-col slice of W_gen (read once into LDS,
// transposed, stride 260 => conflict-free b128 reads). A-fragments read
// directly from L2-resident qbf. C stored directly from registers.
// LDS 66.5 KB -> 2 blocks/CU -> whole grid in one round, no syncs in K-loop.
// ---------------------------------------------------------------------------
__global__ __launch_bounds__(256) void k_params(const bf16* __restrict__ qbf,
                                                const float* __restrict__ Wg,
                                                const float* __restrict__ bg,
                                                bf16* __restrict__ P) {
  __shared__ __align__(16) bf16 BtT[128 * 260];   // [col][q], 66.56 KB

  const int tid  = threadIdx.x;
  const int col0 = blockIdx.x * 128;
  const int wave = tid >> 6, lane = tid & 63;
  const int l15  = lane & 15, lhi = lane >> 4;

  // stage + transpose + bf16 the W_gen slice (once per block)
  for (int i = 0; i < 32; ++i) {
    int idx4 = i * 256 + tid;           // 8192 float4 = 256 q x 32 j4
    int q = idx4 >> 5, j4 = idx4 & 31;
    float4 v = *(const float4*)&Wg[(size_t)q * NCOL + col0 + j4 * 4];
    int cb = j4 * 4;
    BtT[(cb + 0) * 260 + q] = (bf16)v.x;
    BtT[(cb + 1) * 260 + q] = (bf16)v.y;
    BtT[(cb + 2) * 260 + q] = (bf16)v.z;
    BtT[(cb + 3) * 260 + q] = (bf16)v.w;
  }
  __syncthreads();

  // B fragments held in registers for the whole kernel
  b16x8 bfrag[2][8];
  float bcol[2];
#pragma unroll
  for (int nt = 0; nt < 2; ++nt) {
    int col = wave * 32 + nt * 16 + l15;
#pragma unroll
    for (int kk = 0; kk < 8; ++kk)
      bfrag[nt][kk] = *(const b16x8*)&BtT[col * 260 + kk * 32 + lhi * 8];
    bcol[nt] = bg[col0 + col];
  }

  for (int rc = 0; rc < 19; ++rc) {
    int r0 = rc * 64;
    f32x4 acc[4][2] = {};
#pragma unroll
    for (int kk = 0; kk < 8; ++kk)
#pragma unroll
      for (int mt = 0; mt < 4; ++mt) {
        b16x8 af = *(const b16x8*)&qbf[(size_t)(r0 + mt * 16 + l15) * QD + kk * 32 + lhi * 8];
        acc[mt][0] = __builtin_amdgcn_mfma_f32_16x16x32_bf16(af, bfrag[0][kk], acc[mt][0], 0, 0, 0);
        acc[mt][1] = __builtin_amdgcn_mfma_f32_16x16x32_bf16(af, bfrag[1][kk], acc[mt][1], 0, 0, 0);
      }
#pragma unroll
    for (int mt = 0; mt < 4; ++mt) {
      int rbase = r0 + mt * 16 + lhi * 4;
#pragma unroll
      for (int nt = 0; nt < 2; ++nt) {
        size_t cg = (size_t)col0 + wave * 32 + nt * 16 + l15;
#pragma unroll
        for (int r = 0; r < 4; ++r) {
          int row = rbase + r;
          if (row < BN_TOT)
            P[(size_t)row * NCOL + cg] = (bf16)(acc[mt][nt][r] + bcol[nt]);
        }
      }
    }
  }
}

// ---------------------------------------------------------------------------
// K2: per-(bn,g) cascade mix:
//   h1 = relu(x @ M / 8 + M_b);  h2 = relu(S @ h1 + S_b)  -> H[bn][o][g][c]
// x A-fragments loaded global->register (x is stream-once), LDS 66.5 KB ->
// 2 blocks/CU.
// ---------------------------------------------------------------------------
__global__ __launch_bounds__(256) void k_mix(const float* __restrict__ x,
                                             const bf16* __restrict__ P,
                                             const float* __restrict__ mb,
                                             bf16* __restrict__ H) {
  __shared__ __align__(16) bf16 lds[64 * 76 + 32 * 296 + 64 * 296];
  bf16* MtT = lds;                 // [d 0..63][76]  c-contig
  bf16* St  = lds + 64 * 76;       // [o 0..31][296] p-contig
  bf16* h1T = St + 32 * 296;       // [c 0..63][296] p-contig
  __shared__ float mbs[96];

  const int blk = blockIdx.x;
  const int bn = blk >> 2, g = blk & 3;
  const int tid = threadIdx.x;
  const int wave = tid >> 6, lane = tid & 63;
  const int l15 = lane & 15, lhi = lane >> 4;

  const size_t pb = (size_t)bn * NCOL + g * 13312;
  for (int i = 0; i < 4; ++i) {                      // M: 4096, transpose
    int idx4 = i * 256 + tid;
    int c = idx4 >> 4, d4 = (idx4 & 15) * 4;
    b16x4 v = *(const b16x4*)&P[pb + c * 64 + d4];
    MtT[(d4 + 0) * 76 + c] = v[0];
    MtT[(d4 + 1) * 76 + c] = v[1];
    MtT[(d4 + 2) * 76 + c] = v[2];
    MtT[(d4 + 3) * 76 + c] = v[3];
  }
  for (int i = 0; i < 9; ++i) {                      // S: 9216, direct
    int idx4 = i * 256 + tid;
    int o = idx4 / 72, p4 = (idx4 - o * 72) * 4;
    *(b16x4*)&St[o * 296 + p4] = *(const b16x4*)&P[pb + 4096 + (size_t)idx4 * 4];
  }
  if (tid < 96) mbs[tid] = mb[(size_t)bn * 384 + g * 96 + tid];
  __syncthreads();

  // MFMA1: A = x (direct from HBM), B = M; 18 m-tiles round-robin over waves
  b16x8 mfrag[4][2];
  float mbv[4];
#pragma unroll
  for (int nt = 0; nt < 4; ++nt) {
#pragma unroll
    for (int kk = 0; kk < 2; ++kk)
      mfrag[nt][kk] = *(const b16x8*)&MtT[(nt * 16 + l15) * 76 + kk * 32 + lhi * 8];
    mbv[nt] = mbs[nt * 16 + l15];
  }

  const float* xp0 = &x[((size_t)bn * 4 + g) * 18432];
  for (int mt = wave; mt < 18; mt += 4) {
    f32x4 acc[4] = {};
#pragma unroll
    for (int kk = 0; kk < 2; ++kk) {
      const float* xp = xp0 + (mt * 16 + l15) * 64 + kk * 32 + lhi * 8;
      float4 a0 = *(const float4*)xp;
      float4 a1 = *(const float4*)(xp + 4);
      b16x8 af;
      af[0] = (bf16)a0.x; af[1] = (bf16)a0.y; af[2] = (bf16)a0.z; af[3] = (bf16)a0.w;
      af[4] = (bf16)a1.x; af[5] = (bf16)a1.y; af[6] = (bf16)a1.z; af[7] = (bf16)a1.w;
#pragma unroll
      for (int nt = 0; nt < 4; ++nt)
        acc[nt] = __builtin_amdgcn_mfma_f32_16x16x32_bf16(af, mfrag[nt][kk], acc[nt], 0, 0, 0);
    }
#pragma unroll
    for (int nt = 0; nt < 4; ++nt) {
      int d = nt * 16 + l15;
      b16x4 hv;
#pragma unroll
      for (int r = 0; r < 4; ++r) {
        float v = acc[nt][r] * 0.125f + mbv[nt];     // /TEMPER then +M_b
        hv[r] = (bf16)(v > 0.f ? v : 0.f);
      }
      *(b16x4*)&h1T[d * 296 + mt * 16 + lhi * 4] = hv;
    }
  }
  __syncthreads();

  // MFMA2: A = S (32x288), B = h1 (288x64), K=288 in 9 steps
  const int mt2 = wave >> 1;
  const int ntb = (wave & 1) * 2;
  f32x4 acc2[2] = {};
#pragma unroll
  for (int kk = 0; kk < 9; ++kk) {
    b16x8 af = *(const b16x8*)&St[(mt2 * 16 + l15) * 296 + kk * 32 + lhi * 8];
#pragma unroll
    for (int t = 0; t < 2; ++t) {
      b16x8 bf = *(const b16x8*)&h1T[((ntb + t) * 16 + l15) * 296 + kk * 32 + lhi * 8];
      acc2[t] = __builtin_amdgcn_mfma_f32_16x16x32_bf16(af, bf, acc2[t], 0, 0, 0);
    }
  }
  bf16* Hp = H + (size_t)bn * 8192 + g * 64;         // H[bn][o][g][c]
#pragma unroll
  for (int t = 0; t < 2; ++t) {
    int c = (ntb + t) * 16 + l15;
#pragma unroll
    for (int r = 0; r < 4; ++r) {
      int o = mt2 * 16 + lhi * 4 + r;
      float v = acc2[t][r] + mbs[64 + o];
      Hp[o * 256 + c] = (bf16)(v > 0.f ? v : 0.f);
    }
  }
}

// ---------------------------------------------------------------------------
// K3: part[kz] = H[:, kz*1024:+1024] @ W_vT^T   (split-K=8, fp32 partials)
// ---------------------------------------------------------------------------
__global__ __launch_bounds__(256) void k_out(const bf16* __restrict__ H,
                                             const bf16* __restrict__ WvT,
                                             float* __restrict__ part) {
  __shared__ __align__(16) bf16 lds[64 * 72 + 256 * 72];  // 46 KB
  bf16* At  = lds;             // [row 0..63][72]
  bf16* BtT = lds + 64 * 72;   // [col 0..255][72]

  const int tid = threadIdx.x;
  const int wave = tid >> 6, lane = tid & 63;
  const int l15 = lane & 15, lhi = lane >> 4;
  const int r0 = blockIdx.x * 64;
  const int k0 = blockIdx.y * 1024;

  f32x4 acc[4][4] = {};
  for (int it = 0; it < 16; ++it) {
    int kb = k0 + it * 64;
    for (int i = 0; i < 4; ++i) {
      int idx4 = i * 256 + tid;          // 1024 -> 64x64
      int rr = idx4 >> 4, q4 = (idx4 & 15) * 4;
      int row = r0 + rr;
      b16x4 v;
#pragma unroll
      for (int j = 0; j < 4; ++j) v[j] = (bf16)0.f;
      if (row < BN_TOT) v = *(const b16x4*)&H[(size_t)row * 8192 + kb + q4];
      *(b16x4*)&At[rr * 72 + q4] = v;
    }
    for (int i = 0; i < 16; ++i) {
      int idx4 = i * 256 + tid;          // 4096 -> 256x64
      int col = idx4 >> 4, q4 = (idx4 & 15) * 4;
      *(b16x4*)&BtT[col * 72 + q4] = *(const b16x4*)&WvT[(size_t)col * 8192 + kb + q4];
    }
    __syncthreads();
#pragma unroll
    for (int kk = 0; kk < 2; ++kk) {
      b16x8 af[4], bf[4];
#pragma unroll
      for (int mt = 0; mt < 4; ++mt)
        af[mt] = *(const b16x8*)&At[(mt * 16 + l15) * 72 + kk * 32 + lhi * 8];
#pragma unroll
      for (int nt = 0; nt < 4; ++nt)
        bf[nt] = *(const b16x8*)&BtT[(wave * 64 + nt * 16 + l15) * 72 + kk * 32 + lhi * 8];
#pragma unroll
      for (int mt = 0; mt < 4; ++mt)
#pragma unroll
        for (int nt = 0; nt < 4; ++nt)
          acc[mt][nt] = __builtin_amdgcn_mfma_f32_16x16x32_bf16(af[mt], bf[nt], acc[mt][nt], 0, 0, 0);
    }
    __syncthreads();
  }
  const size_t pbase = (size_t)blockIdx.y * BN_TOT * 256;
#pragma unroll
  for (int mt = 0; mt < 4; ++mt)
#pragma unroll
    for (int nt = 0; nt < 4; ++nt) {
      int col = wave * 64 + nt * 16 + l15;
#pragma unroll
      for (int r = 0; r < 4; ++r) {
        int row = r0 + mt * 16 + lhi * 4 + r;
        if (row < BN_TOT) part[pbase + (size_t)row * 256 + col] = acc[mt][nt][r];
      }
    }
}

// ---------------------------------------------------------------------------
// K4: out = LayerNorm(sum_kz part + b_v) * ln_g + ln_b   (one block per row)
// ---------------------------------------------------------------------------
__global__ __launch_bounds__(256) void k_ln(const float* __restrict__ part,
                                            const float* __restrict__ bv,
                                            const float* __restrict__ lng,
                                            const float* __restrict__ lnb,
                                            float* __restrict__ out) {
  __shared__ float red[8];
  const int row = blockIdx.x, c = threadIdx.x;
  const int wave = c >> 6, lane = c & 63;
  float v = bv[c];
  for (int kz = 0; kz < 8; ++kz)
    v += part[((size_t)kz * BN_TOT + row) * 256 + c];
  float s = v;
  for (int off = 32; off > 0; off >>= 1) s += __shfl_xor(s, off);
  if (lane == 0) red[wave] = s;
  __syncthreads();
  float mean = (red[0] + red[1] + red[2] + red[3]) * (1.0f / 256.0f);
  float d = v - mean;
  float q = d * d;
  for (int off = 32; off > 0; off >>= 1) q += __shfl_xor(q, off);
  if (lane == 0) red[4 + wave] = q;
  __syncthreads();
  float var = (red[4] + red[5] + red[6] + red[7]) * (1.0f / 256.0f);
  out[(size_t)row * 256 + c] = d * rsqrtf(var + 1e-5f) * lng[c] + lnb[c];
}

// ---------------------------------------------------------------------------
extern "C" void kernel_launch(void* const* d_in, const int* in_sizes, int n_in,
                              void* d_out, int out_size, void* d_ws, size_t ws_size,
                              hipStream_t stream) {
  const float* x   = (const float*)d_in[0];
  const float* qry = (const float*)d_in[1];
  const float* Wg  = (const float*)d_in[2];
  const float* bg  = (const float*)d_in[3];
  const float* Wb  = (const float*)d_in[4];
  const float* bb  = (const float*)d_in[5];
  const float* Wv  = (const float*)d_in[6];
  const float* bv  = (const float*)d_in[7];
  const float* lng = (const float*)d_in[8];
  const float* lnb = (const float*)d_in[9];
  float* out = (float*)d_out;

  // ws layout (bytes), total 163,323,904 (same footprint as R1):
  char* ws = (char*)d_ws;
  bf16*  P    = (bf16*) (ws + 0);           // params bf16: 1200*53248*2
  bf16*  H    = (bf16*) (ws + 127795200);   // h2 bf16:     1200*8192*2
  float* mbw  = (float*)(ws + 147456000);   // mix bias:    1200*384*4
  bf16*  WvT  = (bf16*) (ws + 149299200);   // W_v^T bf16:  256*8192*2
  float* part = (float*)(ws + 153493504);   // splitK:      8*1200*256*4
  bf16*  qbf  = (bf16*) (ws + 153493504);   // aliased: dead before k_out writes part

  k_twv<<<dim3(128, 4), 256, 0, stream>>>(Wv, WvT);
  k_qbf<<<152, 256, 0, stream>>>(qry, qbf);
  k_mb<<<150, 384, 0, stream>>>(qry, Wb, bb, mbw);
  k_params<<<416, 256, 0, stream>>>(qbf, Wg, bg, P);
  k_mix<<<4800, 256, 0, stream>>>(x, P, mbw, H);
  k_out<<<dim3(19, 8), 256, 0, stream>>>(H, WvT, part);
  k_ln<<<1200, 256, 0, stream>>>(part, bv, lng, lnb, out);
}

// Round 3
// 368.115 us; speedup vs baseline: 1.1704x; 1.0603x over previous
//
#include <hip/hip_runtime.h>

typedef __bf16 bf16;
typedef __bf16 b16x8 __attribute__((ext_vector_type(8)));
typedef __bf16 b16x4 __attribute__((ext_vector_type(4)));
typedef float  f32x4 __attribute__((ext_vector_type(4)));

#define BN_TOT 1200
#define PROWS  1216    // padded row count (multiple of 64)
#define NCOL   53248   // G*(PW+SP) = 4*13312
#define QD     256

// ---------------------------------------------------------------------------
// K0: W_v (8192x256 f32, row-major) -> W_vT (256x8192 bf16), tiled transpose
// ---------------------------------------------------------------------------
__global__ __launch_bounds__(256) void k_twv(const float* __restrict__ Wv,
                                             bf16* __restrict__ WvT) {
  __shared__ float t[64][65];
  const int kb = blockIdx.x * 64, cb = blockIdx.y * 64;
  const int tid = threadIdx.x;
  for (int i = 0; i < 16; ++i) {
    int idx = i * 256 + tid;
    int kk = idx >> 6, cc = idx & 63;
    t[kk][cc] = Wv[(size_t)(kb + kk) * 256 + cb + cc];
  }
  __syncthreads();
  for (int i = 0; i < 16; ++i) {
    int idx = i * 256 + tid;
    int cc = idx >> 6, kk = idx & 63;
    WvT[(size_t)(cb + cc) * 8192 + kb + kk] = (bf16)t[kk][cc];
  }
}

// ---------------------------------------------------------------------------
// K_qbf: query f32 -> bf16, padded to 1216 rows (pad rows zeroed)
// ---------------------------------------------------------------------------
__global__ __launch_bounds__(256) void k_qbf(const float* __restrict__ qry,
                                             bf16* __restrict__ qbf) {
  int gid = blockIdx.x * 256 + threadIdx.x;   // 152 blocks: 1216*256/8 threads
  int base = gid * 8;
  int row = base >> 8;
  b16x8 o;
#pragma unroll
  for (int i = 0; i < 8; ++i) o[i] = (bf16)0.f;
  if (row < BN_TOT) {
    float4 a0 = *(const float4*)&qry[base];
    float4 a1 = *(const float4*)&qry[base + 4];
    o[0] = (bf16)a0.x; o[1] = (bf16)a0.y; o[2] = (bf16)a0.z; o[3] = (bf16)a0.w;
    o[4] = (bf16)a1.x; o[5] = (bf16)a1.y; o[6] = (bf16)a1.z; o[7] = (bf16)a1.w;
  }
  *(b16x8*)&qbf[base] = o;
}

// ---------------------------------------------------------------------------
// K_mb: mb = query @ W_bias + b_bias   (1200 x 384, K=256), fp32 VALU
// ---------------------------------------------------------------------------
__global__ __launch_bounds__(384) void k_mb(const float* __restrict__ qry,
                                            const float* __restrict__ Wb,
                                            const float* __restrict__ bb,
                                            float* __restrict__ mbo) {
  const int j = threadIdx.x;          // 0..383
  const int bn0 = blockIdx.x * 8;     // 150 blocks
  float acc[8] = {0, 0, 0, 0, 0, 0, 0, 0};
  for (int q = 0; q < 256; ++q) {
    float w = Wb[(size_t)q * 384 + j];
#pragma unroll
    for (int i = 0; i < 8; ++i) acc[i] += qry[(size_t)(bn0 + i) * 256 + q] * w;
  }
  float b = bb[j];
#pragma unroll
  for (int i = 0; i < 8; ++i) mbo[(size_t)(bn0 + i) * 384 + j] = acc[i] + b;
}

// ---------------------------------------------------------------------------
// K1: P = bf16(query @ W_gen + b_gen)   (1216 x 53248, K=256)
// 416 blocks; W_gen slice staged q-major [256][132] (conflict-free b64
// writes); B-fragments gathered once (scalar LDS reads, one-time); A read
// direct from L2-resident qbf; unconditional register->global C stores.
// ---------------------------------------------------------------------------
__global__ __launch_bounds__(256) void k_params(const bf16* __restrict__ qbf,
                                                const float* __restrict__ Wg,
                                                const float* __restrict__ bg,
                                                bf16* __restrict__ P) {
  __shared__ __align__(16) bf16 Bq[256 * 132];   // [q][col], 67.6 KB

  const int tid  = threadIdx.x;
  const int col0 = blockIdx.x * 128;
  const int wave = tid >> 6, lane = tid & 63;
  const int l15  = lane & 15, lhi = lane >> 4;

  for (int i = 0; i < 32; ++i) {
    int idx4 = i * 256 + tid;           // 8192 float4 = 256 q x 32 j4
    int q = idx4 >> 5, j4 = idx4 & 31;
    float4 v = *(const float4*)&Wg[(size_t)q * NCOL + col0 + j4 * 4];
    b16x4 w;
    w[0] = (bf16)v.x; w[1] = (bf16)v.y; w[2] = (bf16)v.z; w[3] = (bf16)v.w;
    *(b16x4*)&Bq[q * 132 + j4 * 4] = w;
  }
  __syncthreads();

  // one-time B fragment gather (held in registers for the whole kernel)
  b16x8 bfrag[2][8];
  float bcol[2];
#pragma unroll
  for (int nt = 0; nt < 2; ++nt) {
    int col = wave * 32 + nt * 16 + l15;
#pragma unroll
    for (int kk = 0; kk < 8; ++kk)
#pragma unroll
      for (int j = 0; j < 8; ++j)
        bfrag[nt][kk][j] = Bq[(kk * 32 + lhi * 8 + j) * 132 + col];
    bcol[nt] = bg[col0 + col];
  }

  for (int rc = 0; rc < 19; ++rc) {
    int r0 = rc * 64;
    f32x4 acc[4][2] = {};
#pragma unroll
    for (int kk = 0; kk < 8; ++kk)
#pragma unroll
      for (int mt = 0; mt < 4; ++mt) {
        b16x8 af = *(const b16x8*)&qbf[(size_t)(r0 + mt * 16 + l15) * QD + kk * 32 + lhi * 8];
        acc[mt][0] = __builtin_amdgcn_mfma_f32_16x16x32_bf16(af, bfrag[0][kk], acc[mt][0], 0, 0, 0);
        acc[mt][1] = __builtin_amdgcn_mfma_f32_16x16x32_bf16(af, bfrag[1][kk], acc[mt][1], 0, 0, 0);
      }
#pragma unroll
    for (int mt = 0; mt < 4; ++mt) {
      int rbase = r0 + mt * 16 + lhi * 4;
#pragma unroll
      for (int nt = 0; nt < 2; ++nt) {
        size_t cg = (size_t)col0 + wave * 32 + nt * 16 + l15;
        bf16* pp = &P[(size_t)rbase * NCOL + cg];
#pragma unroll
        for (int r = 0; r < 4; ++r)
          pp[(size_t)r * NCOL] = (bf16)(acc[mt][nt][r] + bcol[nt]);
      }
    }
  }
}

// ---------------------------------------------------------------------------
// K2: per-(bn,g) cascade mix. M/S fragments direct from P (L2 dedups the
// wave-pair redundancy); x direct from HBM; only h1T in LDS -> 37.9 KB ->
// 4 blocks/CU; single barrier per block.
// ---------------------------------------------------------------------------
__global__ __launch_bounds__(256, 4) void k_mix(const float* __restrict__ x,
                                                const bf16* __restrict__ P,
                                                const float* __restrict__ mb,
                                                bf16* __restrict__ H) {
  __shared__ __align__(16) bf16 h1T[64 * 296];   // [d][p], 37.9 KB

  const int blk = blockIdx.x;
  const int bn = blk >> 2, g = blk & 3;
  const int tid = threadIdx.x;
  const int wave = tid >> 6, lane = tid & 63;
  const int l15 = lane & 15, lhi = lane >> 4;

  const size_t pb = (size_t)bn * NCOL + g * 13312;
  const float* mbp = mb + (size_t)bn * 384 + g * 96;

  // M fragments (B-operand [k=c][n=d]) direct from P, scalar gather
  b16x8 mfrag[4][2];
  float mbv[4];
#pragma unroll
  for (int nt = 0; nt < 4; ++nt) {
    int d = nt * 16 + l15;
    mbv[nt] = mbp[d];
#pragma unroll
    for (int kk = 0; kk < 2; ++kk) {
      const bf16* mp = &P[pb + (size_t)(kk * 32 + lhi * 8) * 64 + d];
#pragma unroll
      for (int j = 0; j < 8; ++j) mfrag[nt][kk][j] = mp[(size_t)j * 64];
    }
  }

  // MFMA1: h1 = relu(x @ M * 0.125 + M_b), A = x streamed from HBM
  const float* xp0 = &x[((size_t)bn * 4 + g) * 18432];
#pragma unroll
  for (int m0 = 0; m0 < 5; ++m0) {
    int mt = wave + m0 * 4;
    if (mt < 18) {
      f32x4 acc[4] = {};
#pragma unroll
      for (int kk = 0; kk < 2; ++kk) {
        const float* xp = xp0 + (mt * 16 + l15) * 64 + kk * 32 + lhi * 8;
        float4 a0 = *(const float4*)xp;
        float4 a1 = *(const float4*)(xp + 4);
        b16x8 af;
        af[0] = (bf16)a0.x; af[1] = (bf16)a0.y; af[2] = (bf16)a0.z; af[3] = (bf16)a0.w;
        af[4] = (bf16)a1.x; af[5] = (bf16)a1.y; af[6] = (bf16)a1.z; af[7] = (bf16)a1.w;
#pragma unroll
        for (int nt = 0; nt < 4; ++nt)
          acc[nt] = __builtin_amdgcn_mfma_f32_16x16x32_bf16(af, mfrag[nt][kk], acc[nt], 0, 0, 0);
      }
#pragma unroll
      for (int nt = 0; nt < 4; ++nt) {
        int d = nt * 16 + l15;
        b16x4 hv;
#pragma unroll
        for (int r = 0; r < 4; ++r) {
          float v = acc[nt][r] * 0.125f + mbv[nt];   // /TEMPER then +M_b
          hv[r] = (bf16)(v > 0.f ? v : 0.f);
        }
        *(b16x4*)&h1T[d * 296 + mt * 16 + lhi * 4] = hv;
      }
    }
  }
  __syncthreads();

  // MFMA2: h2 = relu(S @ h1 + S_b); S fragments direct from P
  const int mt2 = wave >> 1;
  const int ntb = (wave & 1) * 2;
  const bf16* Sp = &P[pb + 4096];
  f32x4 acc2[2] = {};
#pragma unroll
  for (int kk = 0; kk < 9; ++kk) {
    b16x8 af = *(const b16x8*)&Sp[(size_t)(mt2 * 16 + l15) * 288 + kk * 32 + lhi * 8];
#pragma unroll
    for (int t = 0; t < 2; ++t) {
      b16x8 bfv = *(const b16x8*)&h1T[((ntb + t) * 16 + l15) * 296 + kk * 32 + lhi * 8];
      acc2[t] = __builtin_amdgcn_mfma_f32_16x16x32_bf16(af, bfv, acc2[t], 0, 0, 0);
    }
  }
  bf16* Hp = H + (size_t)bn * 8192 + g * 64;       // H[bn][o][g][c]
#pragma unroll
  for (int r = 0; r < 4; ++r) {
    int o = mt2 * 16 + lhi * 4 + r;
    float sb = mbp[64 + o];
#pragma unroll
    for (int t = 0; t < 2; ++t) {
      float v = acc2[t][r] + sb;
      Hp[o * 256 + (ntb + t) * 16 + l15] = (bf16)(v > 0.f ? v : 0.f);
    }
  }
}

// ---------------------------------------------------------------------------
// K3: part[kz] = H[:, kz*512:+512] @ W_vT^T   (split-K=16, fp32 partials)
// LDS-free, sync-free: A from H (L3), B from WvT (L3), register fragments.
// ---------------------------------------------------------------------------
__global__ __launch_bounds__(256) void k_out(const bf16* __restrict__ H,
                                             const bf16* __restrict__ WvT,
                                             float* __restrict__ part) {
  const int tid = threadIdx.x;
  const int wave = tid >> 6, lane = tid & 63;
  const int l15 = lane & 15, lhi = lane >> 4;
  const int r0 = blockIdx.x * 64;
  const int k0 = blockIdx.y * 512;

  f32x4 acc[4][4] = {};
  for (int it = 0; it < 8; ++it) {
    int kb = k0 + it * 64;
    b16x8 bfv[2][4], afv[2][4];
#pragma unroll
    for (int kk = 0; kk < 2; ++kk)
#pragma unroll
      for (int nt = 0; nt < 4; ++nt)
        bfv[kk][nt] = *(const b16x8*)&WvT[(size_t)(wave * 64 + nt * 16 + l15) * 8192 + kb + kk * 32 + lhi * 8];
#pragma unroll
    for (int kk = 0; kk < 2; ++kk)
#pragma unroll
      for (int mt = 0; mt < 4; ++mt)
        afv[kk][mt] = *(const b16x8*)&H[(size_t)(r0 + mt * 16 + l15) * 8192 + kb + kk * 32 + lhi * 8];
#pragma unroll
    for (int kk = 0; kk < 2; ++kk)
#pragma unroll
      for (int mt = 0; mt < 4; ++mt)
#pragma unroll
        for (int nt = 0; nt < 4; ++nt)
          acc[mt][nt] = __builtin_amdgcn_mfma_f32_16x16x32_bf16(afv[kk][mt], bfv[kk][nt], acc[mt][nt], 0, 0, 0);
  }
  const size_t pbase = (size_t)blockIdx.y * PROWS * 256;
#pragma unroll
  for (int mt = 0; mt < 4; ++mt)
#pragma unroll
    for (int nt = 0; nt < 4; ++nt) {
      int col = wave * 64 + nt * 16 + l15;
#pragma unroll
      for (int r = 0; r < 4; ++r) {
        int row = r0 + mt * 16 + lhi * 4 + r;
        part[pbase + (size_t)row * 256 + col] = acc[mt][nt][r];
      }
    }
}

// ---------------------------------------------------------------------------
// K4: out = LayerNorm(sum_kz part + b_v) * ln_g + ln_b   (one block per row)
// ---------------------------------------------------------------------------
__global__ __launch_bounds__(256) void k_ln(const float* __restrict__ part,
                                            const float* __restrict__ bv,
                                            const float* __restrict__ lng,
                                            const float* __restrict__ lnb,
                                            float* __restrict__ out) {
  __shared__ float red[8];
  const int row = blockIdx.x, c = threadIdx.x;
  const int wave = c >> 6, lane = c & 63;
  float v = bv[c];
  for (int kz = 0; kz < 16; ++kz)
    v += part[((size_t)kz * PROWS + row) * 256 + c];
  float s = v;
  for (int off = 32; off > 0; off >>= 1) s += __shfl_xor(s, off);
  if (lane == 0) red[wave] = s;
  __syncthreads();
  float mean = (red[0] + red[1] + red[2] + red[3]) * (1.0f / 256.0f);
  float d = v - mean;
  float q = d * d;
  for (int off = 32; off > 0; off >>= 1) q += __shfl_xor(q, off);
  if (lane == 0) red[4 + wave] = q;
  __syncthreads();
  float var = (red[4] + red[5] + red[6] + red[7]) * (1.0f / 256.0f);
  out[(size_t)row * 256 + c] = d * rsqrtf(var + 1e-5f) * lng[c] + lnb[c];
}

// ---------------------------------------------------------------------------
extern "C" void kernel_launch(void* const* d_in, const int* in_sizes, int n_in,
                              void* d_out, int out_size, void* d_ws, size_t ws_size,
                              hipStream_t stream) {
  const float* x   = (const float*)d_in[0];
  const float* qry = (const float*)d_in[1];
  const float* Wg  = (const float*)d_in[2];
  const float* bg  = (const float*)d_in[3];
  const float* Wb  = (const float*)d_in[4];
  const float* bb  = (const float*)d_in[5];
  const float* Wv  = (const float*)d_in[6];
  const float* bv  = (const float*)d_in[7];
  const float* lng = (const float*)d_in[8];
  const float* lnb = (const float*)d_in[9];
  float* out = (float*)d_out;

  // ws layout (bytes), total ~175.4 MB (ws is ~1.4 GB per harness fills):
  char* ws = (char*)d_ws;
  bf16*  P    = (bf16*) (ws + 0);           // params bf16: 1216*53248*2 = 129,499,136
  bf16*  H    = (bf16*) (ws + 129499136);   // h2 bf16:     1216*8192*2  = 19,922,944
  float* mbw  = (float*)(ws + 149422080);   // mix bias:    1200*384*4   = 1,843,200
  bf16*  WvT  = (bf16*) (ws + 151265280);   // W_v^T bf16:  256*8192*2   = 4,194,304
  float* part = (float*)(ws + 155459584);   // splitK:      16*1216*256*4 = 19,922,944
  bf16*  qbf  = (bf16*) (ws + 155459584);   // aliased over part (dead before k_out)

  k_twv<<<dim3(128, 4), 256, 0, stream>>>(Wv, WvT);
  k_qbf<<<152, 256, 0, stream>>>(qry, qbf);
  k_mb<<<150, 384, 0, stream>>>(qry, Wb, bb, mbw);
  k_params<<<416, 256, 0, stream>>>(qbf, Wg, bg, P);
  k_mix<<<4800, 256, 0, stream>>>(x, P, mbw, H);
  k_out<<<dim3(19, 16), 256, 0, stream>>>(H, WvT, part);
  k_ln<<<1200, 256, 0, stream>>>(part, bv, lng, lnb, out);
}

// Round 4
// 265.143 us; speedup vs baseline: 1.6250x; 1.3884x over previous
//
#include <hip/hip_runtime.h>

typedef __bf16 bf16;
typedef __bf16 b16x8 __attribute__((ext_vector_type(8)));
typedef __bf16 b16x4 __attribute__((ext_vector_type(4)));
typedef float  f32x4 __attribute__((ext_vector_type(4)));

#define BN_TOT 1200
#define PROWS  1216    // padded row count (multiple of 64)
#define NCOL   53248   // G*(PW+SP) = 4*13312
#define QD     256

// ---------------------------------------------------------------------------
// K0: W_v (8192x256 f32, row-major) -> W_vT (256x8192 bf16), tiled transpose
// ---------------------------------------------------------------------------
__global__ __launch_bounds__(256) void k_twv(const float* __restrict__ Wv,
                                             bf16* __restrict__ WvT) {
  __shared__ float t[64][65];
  const int kb = blockIdx.x * 64, cb = blockIdx.y * 64;
  const int tid = threadIdx.x;
  for (int i = 0; i < 16; ++i) {
    int idx = i * 256 + tid;
    int kk = idx >> 6, cc = idx & 63;
    t[kk][cc] = Wv[(size_t)(kb + kk) * 256 + cb + cc];
  }
  __syncthreads();
  for (int i = 0; i < 16; ++i) {
    int idx = i * 256 + tid;
    int cc = idx >> 6, kk = idx & 63;
    WvT[(size_t)(cb + cc) * 8192 + kb + kk] = (bf16)t[kk][cc];
  }
}

// ---------------------------------------------------------------------------
// K_qbf: query f32 -> bf16, padded to 1216 rows (pad rows zeroed)
// ---------------------------------------------------------------------------
__global__ __launch_bounds__(256) void k_qbf(const float* __restrict__ qry,
                                             bf16* __restrict__ qbf) {
  int gid = blockIdx.x * 256 + threadIdx.x;   // 152 blocks: 1216*256/8 threads
  int base = gid * 8;
  int row = base >> 8;
  b16x8 o;
#pragma unroll
  for (int i = 0; i < 8; ++i) o[i] = (bf16)0.f;
  if (row < BN_TOT) {
    float4 a0 = *(const float4*)&qry[base];
    float4 a1 = *(const float4*)&qry[base + 4];
    o[0] = (bf16)a0.x; o[1] = (bf16)a0.y; o[2] = (bf16)a0.z; o[3] = (bf16)a0.w;
    o[4] = (bf16)a1.x; o[5] = (bf16)a1.y; o[6] = (bf16)a1.z; o[7] = (bf16)a1.w;
  }
  *(b16x8*)&qbf[base] = o;
}

// ---------------------------------------------------------------------------
// K_mb: mb = query @ W_bias + b_bias   (1200 x 384, K=256), fp32 VALU
// ---------------------------------------------------------------------------
__global__ __launch_bounds__(384) void k_mb(const float* __restrict__ qry,
                                            const float* __restrict__ Wb,
                                            const float* __restrict__ bb,
                                            float* __restrict__ mbo) {
  const int j = threadIdx.x;          // 0..383
  const int bn0 = blockIdx.x * 8;     // 150 blocks
  float acc[8] = {0, 0, 0, 0, 0, 0, 0, 0};
  for (int q = 0; q < 256; ++q) {
    float w = Wb[(size_t)q * 384 + j];
#pragma unroll
    for (int i = 0; i < 8; ++i) acc[i] += qry[(size_t)(bn0 + i) * 256 + q] * w;
  }
  float b = bb[j];
#pragma unroll
  for (int i = 0; i < 8; ++i) mbo[(size_t)(bn0 + i) * 384 + j] = acc[i] + b;
}

// ---------------------------------------------------------------------------
// K1: P = bf16(query @ W_gen + b_gen)   (1216 x 53248, K=256)
// 416 blocks. Phase 1: stage Wg slice q-major in LDS, gather B-fragments to
// registers (LDS then dead). Phase 2: double-buffered A-tiles (64x256 bf16,
// 32 KB each) staged via global_load_lds (16B, pre-swizzled source; XOR
// swizzle on ds_read_b128 -> 2-way = free), 2-phase pipeline, one barrier/rc.
// ---------------------------------------------------------------------------
__global__ __launch_bounds__(256) void k_params(const bf16* __restrict__ qbf,
                                                const float* __restrict__ Wg,
                                                const float* __restrict__ bg,
                                                bf16* __restrict__ P) {
  __shared__ __align__(16) bf16 lds[256 * 132];   // 67.6 KB: Bq, then A dbuf

  const int tid  = threadIdx.x;
  const int col0 = blockIdx.x * 128;
  const int wave = tid >> 6, lane = tid & 63;
  const int l15  = lane & 15, lhi = lane >> 4;

  // ---- Phase 1: B fragments ----
  for (int i = 0; i < 32; ++i) {
    int idx4 = i * 256 + tid;           // 8192 float4 = 256 q x 32 j4
    int q = idx4 >> 5, j4 = idx4 & 31;
    float4 v = *(const float4*)&Wg[(size_t)q * NCOL + col0 + j4 * 4];
    b16x4 w;
    w[0] = (bf16)v.x; w[1] = (bf16)v.y; w[2] = (bf16)v.z; w[3] = (bf16)v.w;
    *(b16x4*)&lds[q * 132 + j4 * 4] = w;
  }
  __syncthreads();

  b16x8 bfrag[2][8];
  float bcol[2];
#pragma unroll
  for (int nt = 0; nt < 2; ++nt) {
    int col = wave * 32 + nt * 16 + l15;
#pragma unroll
    for (int kk = 0; kk < 8; ++kk)
#pragma unroll
      for (int j = 0; j < 8; ++j)
        bfrag[nt][kk][j] = lds[(kk * 32 + lhi * 8 + j) * 132 + col];
    bcol[nt] = bg[col0 + col];
  }
  __syncthreads();   // Bq dead; LDS becomes A double-buffer

  // ---- Phase 2: K-loop over 19 row-tiles ----
  // stage A tile rc into buffer b: 64 rows x 512 B, swizzled 16B chunks
  const char* qb = (const char*)qbf;
#define STAGE_A(b, rc)                                                         \
  {                                                                            \
    const char* s0 = qb + (size_t)(rc) * 64 * 512;                             \
    _Pragma("unroll")                                                          \
    for (int i = 0; i < 8; ++i) {                                              \
      int c = i * 256 + wave * 64 + lane;                                      \
      int r = c >> 5;                                                          \
      int boff = ((c & 31) << 4) ^ ((r & 7) << 4);                             \
      const void* src = (const void*)(s0 + r * 512 + boff);                    \
      bf16* dst = &lds[(b) * 16384 + (size_t)(i * 256 + wave * 64) * 8];       \
      __builtin_amdgcn_global_load_lds(                                        \
          (const __attribute__((address_space(1))) void*)src,                  \
          (__attribute__((address_space(3))) void*)dst, 16, 0, 0);             \
    }                                                                          \
  }

  STAGE_A(0, 0);
  __syncthreads();   // drain prologue staging

  for (int rc = 0; rc < 19; ++rc) {
    int cur = rc & 1;
    if (rc + 1 < 19) STAGE_A(cur ^ 1, rc + 1);   // prefetch flies under compute

    const bf16* At = &lds[cur * 16384];
    int r0 = rc * 64;
    f32x4 acc[4][2] = {};
#pragma unroll
    for (int kk = 0; kk < 8; ++kk)
#pragma unroll
      for (int mt = 0; mt < 4; ++mt) {
        int row = mt * 16 + l15;
        int coff = (kk * 32 + lhi * 8) ^ ((l15 & 7) << 3);
        b16x8 af = *(const b16x8*)&At[row * 256 + coff];
        acc[mt][0] = __builtin_amdgcn_mfma_f32_16x16x32_bf16(af, bfrag[0][kk], acc[mt][0], 0, 0, 0);
        acc[mt][1] = __builtin_amdgcn_mfma_f32_16x16x32_bf16(af, bfrag[1][kk], acc[mt][1], 0, 0, 0);
      }
#pragma unroll
    for (int mt = 0; mt < 4; ++mt) {
      int rbase = r0 + mt * 16 + lhi * 4;
#pragma unroll
      for (int nt = 0; nt < 2; ++nt) {
        size_t cg = (size_t)col0 + wave * 32 + nt * 16 + l15;
        bf16* pp = &P[(size_t)rbase * NCOL + cg];
#pragma unroll
        for (int r = 0; r < 4; ++r)
          pp[(size_t)r * NCOL] = (bf16)(acc[mt][nt][r] + bcol[nt]);
      }
    }
    __syncthreads();   // prefetch complete + buffer safe to overwrite
  }
#undef STAGE_A
}

// ---------------------------------------------------------------------------
// K2: per-(bn,g) cascade mix. M/S fragments direct from P (L3-resident);
// S prefetched to registers BEFORE the barrier so MFMA2 has no global
// latency; x direct from HBM; h1T only in LDS (37.9 KB).
// ---------------------------------------------------------------------------
__global__ __launch_bounds__(256, 3) void k_mix(const float* __restrict__ x,
                                                const bf16* __restrict__ P,
                                                const float* __restrict__ mb,
                                                bf16* __restrict__ H) {
  __shared__ __align__(16) bf16 h1T[64 * 296];   // [d][p], 37.9 KB

  const int blk = blockIdx.x;
  const int bn = blk >> 2, g = blk & 3;
  const int tid = threadIdx.x;
  const int wave = tid >> 6, lane = tid & 63;
  const int l15 = lane & 15, lhi = lane >> 4;

  const size_t pb = (size_t)bn * NCOL + g * 13312;
  const float* mbp = mb + (size_t)bn * 384 + g * 96;

  // M fragments (B-operand [k=c][n=d]) direct from P, scalar gather
  b16x8 mfrag[4][2];
  float mbv[4];
#pragma unroll
  for (int nt = 0; nt < 4; ++nt) {
    int d = nt * 16 + l15;
    mbv[nt] = mbp[d];
#pragma unroll
    for (int kk = 0; kk < 2; ++kk) {
      const bf16* mp = &P[pb + (size_t)(kk * 32 + lhi * 8) * 64 + d];
#pragma unroll
      for (int j = 0; j < 8; ++j) mfrag[nt][kk][j] = mp[(size_t)j * 64];
    }
  }

  // S fragments + S_b prefetched now (independent of h1) — MFMA2 phase
  // then runs entirely from registers + LDS.
  const int mt2 = wave >> 1;
  const int ntb = (wave & 1) * 2;
  const bf16* Sp = &P[pb + 4096];
  b16x8 sfrag[9];
#pragma unroll
  for (int kk = 0; kk < 9; ++kk)
    sfrag[kk] = *(const b16x8*)&Sp[(size_t)(mt2 * 16 + l15) * 288 + kk * 32 + lhi * 8];
  float sbv[4];
#pragma unroll
  for (int r = 0; r < 4; ++r) sbv[r] = mbp[64 + mt2 * 16 + lhi * 4 + r];

  // MFMA1: h1 = relu(x @ M * 0.125 + M_b), A = x streamed from HBM
  const float* xp0 = &x[((size_t)bn * 4 + g) * 18432];
#pragma unroll
  for (int m0 = 0; m0 < 5; ++m0) {
    int mt = wave + m0 * 4;
    if (mt < 18) {
      f32x4 acc[4] = {};
#pragma unroll
      for (int kk = 0; kk < 2; ++kk) {
        const float* xp = xp0 + (mt * 16 + l15) * 64 + kk * 32 + lhi * 8;
        float4 a0 = *(const float4*)xp;
        float4 a1 = *(const float4*)(xp + 4);
        b16x8 af;
        af[0] = (bf16)a0.x; af[1] = (bf16)a0.y; af[2] = (bf16)a0.z; af[3] = (bf16)a0.w;
        af[4] = (bf16)a1.x; af[5] = (bf16)a1.y; af[6] = (bf16)a1.z; af[7] = (bf16)a1.w;
#pragma unroll
        for (int nt = 0; nt < 4; ++nt)
          acc[nt] = __builtin_amdgcn_mfma_f32_16x16x32_bf16(af, mfrag[nt][kk], acc[nt], 0, 0, 0);
      }
#pragma unroll
      for (int nt = 0; nt < 4; ++nt) {
        int d = nt * 16 + l15;
        b16x4 hv;
#pragma unroll
        for (int r = 0; r < 4; ++r) {
          float v = acc[nt][r] * 0.125f + mbv[nt];   // /TEMPER then +M_b
          hv[r] = (bf16)(v > 0.f ? v : 0.f);
        }
        *(b16x4*)&h1T[d * 296 + mt * 16 + lhi * 4] = hv;
      }
    }
  }
  __syncthreads();

  // MFMA2: h2 = relu(S @ h1 + S_b), S already in registers
  f32x4 acc2[2] = {};
#pragma unroll
  for (int kk = 0; kk < 9; ++kk) {
#pragma unroll
    for (int t = 0; t < 2; ++t) {
      b16x8 bfv = *(const b16x8*)&h1T[((ntb + t) * 16 + l15) * 296 + kk * 32 + lhi * 8];
      acc2[t] = __builtin_amdgcn_mfma_f32_16x16x32_bf16(sfrag[kk], bfv, acc2[t], 0, 0, 0);
    }
  }
  bf16* Hp = H + (size_t)bn * 8192 + g * 64;       // H[bn][o][g][c]
#pragma unroll
  for (int r = 0; r < 4; ++r) {
    int o = mt2 * 16 + lhi * 4 + r;
#pragma unroll
    for (int t = 0; t < 2; ++t) {
      float v = acc2[t][r] + sbv[r];
      Hp[o * 256 + (ntb + t) * 16 + l15] = (bf16)(v > 0.f ? v : 0.f);
    }
  }
}

// ---------------------------------------------------------------------------
// K3: part[kz] = H[:, kz*512:+512] @ W_vT^T   (split-K=16, fp32 partials)
// LDS-free, sync-free: A from H (L3), B from WvT (L3), register fragments.
// ---------------------------------------------------------------------------
__global__ __launch_bounds__(256) void k_out(const bf16* __restrict__ H,
                                             const bf16* __restrict__ WvT,
                                             float* __restrict__ part) {
  const int tid = threadIdx.x;
  const int wave = tid >> 6, lane = tid & 63;
  const int l15 = lane & 15, lhi = lane >> 4;
  const int r0 = blockIdx.x * 64;
  const int k0 = blockIdx.y * 512;

  f32x4 acc[4][4] = {};
  for (int it = 0; it < 8; ++it) {
    int kb = k0 + it * 64;
    b16x8 bfv[2][4], afv[2][4];
#pragma unroll
    for (int kk = 0; kk < 2; ++kk)
#pragma unroll
      for (int nt = 0; nt < 4; ++nt)
        bfv[kk][nt] = *(const b16x8*)&WvT[(size_t)(wave * 64 + nt * 16 + l15) * 8192 + kb + kk * 32 + lhi * 8];
#pragma unroll
    for (int kk = 0; kk < 2; ++kk)
#pragma unroll
      for (int mt = 0; mt < 4; ++mt)
        afv[kk][mt] = *(const b16x8*)&H[(size_t)(r0 + mt * 16 + l15) * 8192 + kb + kk * 32 + lhi * 8];
#pragma unroll
    for (int kk = 0; kk < 2; ++kk)
#pragma unroll
      for (int mt = 0; mt < 4; ++mt)
#pragma unroll
        for (int nt = 0; nt < 4; ++nt)
          acc[mt][nt] = __builtin_amdgcn_mfma_f32_16x16x32_bf16(afv[kk][mt], bfv[kk][nt], acc[mt][nt], 0, 0, 0);
  }
  const size_t pbase = (size_t)blockIdx.y * PROWS * 256;
#pragma unroll
  for (int mt = 0; mt < 4; ++mt)
#pragma unroll
    for (int nt = 0; nt < 4; ++nt) {
      int col = wave * 64 + nt * 16 + l15;
#pragma unroll
      for (int r = 0; r < 4; ++r) {
        int row = r0 + mt * 16 + lhi * 4 + r;
        part[pbase + (size_t)row * 256 + col] = acc[mt][nt][r];
      }
    }
}

// ---------------------------------------------------------------------------
// K4: out = LayerNorm(sum_kz part + b_v) * ln_g + ln_b   (one block per row)
// ---------------------------------------------------------------------------
__global__ __launch_bounds__(256) void k_ln(const float* __restrict__ part,
                                            const float* __restrict__ bv,
                                            const float* __restrict__ lng,
                                            const float* __restrict__ lnb,
                                            float* __restrict__ out) {
  __shared__ float red[8];
  const int row = blockIdx.x, c = threadIdx.x;
  const int wave = c >> 6, lane = c & 63;
  float v = bv[c];
  for (int kz = 0; kz < 16; ++kz)
    v += part[((size_t)kz * PROWS + row) * 256 + c];
  float s = v;
  for (int off = 32; off > 0; off >>= 1) s += __shfl_xor(s, off);
  if (lane == 0) red[wave] = s;
  __syncthreads();
  float mean = (red[0] + red[1] + red[2] + red[3]) * (1.0f / 256.0f);
  float d = v - mean;
  float q = d * d;
  for (int off = 32; off > 0; off >>= 1) q += __shfl_xor(q, off);
  if (lane == 0) red[4 + wave] = q;
  __syncthreads();
  float var = (red[4] + red[5] + red[6] + red[7]) * (1.0f / 256.0f);
  out[(size_t)row * 256 + c] = d * rsqrtf(var + 1e-5f) * lng[c] + lnb[c];
}

// ---------------------------------------------------------------------------
extern "C" void kernel_launch(void* const* d_in, const int* in_sizes, int n_in,
                              void* d_out, int out_size, void* d_ws, size_t ws_size,
                              hipStream_t stream) {
  const float* x   = (const float*)d_in[0];
  const float* qry = (const float*)d_in[1];
  const float* Wg  = (const float*)d_in[2];
  const float* bg  = (const float*)d_in[3];
  const float* Wb  = (const float*)d_in[4];
  const float* bb  = (const float*)d_in[5];
  const float* Wv  = (const float*)d_in[6];
  const float* bv  = (const float*)d_in[7];
  const float* lng = (const float*)d_in[8];
  const float* lnb = (const float*)d_in[9];
  float* out = (float*)d_out;

  // ws layout (bytes):
  char* ws = (char*)d_ws;
  bf16*  P    = (bf16*) (ws + 0);           // params bf16: 1216*53248*2 = 129,499,136
  bf16*  H    = (bf16*) (ws + 129499136);   // h2 bf16:     1216*8192*2  = 19,922,944
  float* mbw  = (float*)(ws + 149422080);   // mix bias:    1200*384*4   = 1,843,200
  bf16*  WvT  = (bf16*) (ws + 151265280);   // W_v^T bf16:  256*8192*2   = 4,194,304
  float* part = (float*)(ws + 155459584);   // splitK:      16*1216*256*4 = 19,922,944
  bf16*  qbf  = (bf16*) (ws + 155459584);   // aliased over part (dead before k_out)

  k_twv<<<dim3(128, 4), 256, 0, stream>>>(Wv, WvT);
  k_qbf<<<152, 256, 0, stream>>>(qry, qbf);
  k_mb<<<150, 384, 0, stream>>>(qry, Wb, bb, mbw);
  k_params<<<416, 256, 0, stream>>>(qbf, Wg, bg, P);
  k_mix<<<4800, 256, 0, stream>>>(x, P, mbw, H);
  k_out<<<dim3(19, 16), 256, 0, stream>>>(H, WvT, part);
  k_ln<<<1200, 256, 0, stream>>>(part, bv, lng, lnb, out);
}

// Round 6
// 262.782 us; speedup vs baseline: 1.6396x; 1.0090x over previous
//
#include <hip/hip_runtime.h>

typedef __bf16 bf16;
typedef __bf16 b16x8 __attribute__((ext_vector_type(8)));
typedef __bf16 b16x4 __attribute__((ext_vector_type(4)));
typedef float  f32x4 __attribute__((ext_vector_type(4)));

#define BN_TOT 1200
#define PROWS  1216    // padded row count (multiple of 64)
#define NCOL   53248   // G*(PW+SP) = 4*13312
#define QD     256

// ---------------------------------------------------------------------------
// K_pre: fused preprocessing, blockIdx-partitioned:
//   [0,512)   : W_v transpose -> WvT bf16
//   [512,664) : query f32 -> bf16 padded to 1216 rows
//   [664,814) : mb = query @ W_bias + b_bias
// ---------------------------------------------------------------------------
__global__ __launch_bounds__(256) void k_pre(const float* __restrict__ Wv,
                                             bf16* __restrict__ WvT,
                                             const float* __restrict__ qry,
                                             bf16* __restrict__ qbf,
                                             const float* __restrict__ Wb,
                                             const float* __restrict__ bb,
                                             float* __restrict__ mbo) {
  const int b = blockIdx.x;
  const int tid = threadIdx.x;
  if (b < 512) {
    __shared__ float t[64][65];
    const int kb = (b & 127) * 64, cb = (b >> 7) * 64;
    for (int i = 0; i < 16; ++i) {
      int idx = i * 256 + tid;
      int kk = idx >> 6, cc = idx & 63;
      t[kk][cc] = Wv[(size_t)(kb + kk) * 256 + cb + cc];
    }
    __syncthreads();
    for (int i = 0; i < 16; ++i) {
      int idx = i * 256 + tid;
      int cc = idx >> 6, kk = idx & 63;
      WvT[(size_t)(cb + cc) * 8192 + kb + kk] = (bf16)t[kk][cc];
    }
  } else if (b < 664) {
    int gid = (b - 512) * 256 + tid;
    int base = gid * 8;
    int row = base >> 8;
    b16x8 o;
#pragma unroll
    for (int i = 0; i < 8; ++i) o[i] = (bf16)0.f;
    if (row < BN_TOT) {
      float4 a0 = *(const float4*)&qry[base];
      float4 a1 = *(const float4*)&qry[base + 4];
      o[0] = (bf16)a0.x; o[1] = (bf16)a0.y; o[2] = (bf16)a0.z; o[3] = (bf16)a0.w;
      o[4] = (bf16)a1.x; o[5] = (bf16)a1.y; o[6] = (bf16)a1.z; o[7] = (bf16)a1.w;
    }
    *(b16x8*)&qbf[base] = o;
  } else {
    const int bn0 = (b - 664) * 8;
    const int j1 = tid;
    const int j2 = 256 + (tid & 127);
    float a1[8] = {}, a2[8] = {};
    for (int q = 0; q < 256; ++q) {
      float w1 = Wb[(size_t)q * 384 + j1];
      float w2 = Wb[(size_t)q * 384 + j2];
#pragma unroll
      for (int i = 0; i < 8; ++i) {
        float qv = qry[(size_t)(bn0 + i) * 256 + q];
        a1[i] += qv * w1; a2[i] += qv * w2;
      }
    }
    float b1 = bb[j1], b2 = bb[j2];
#pragma unroll
    for (int i = 0; i < 8; ++i) mbo[(size_t)(bn0 + i) * 384 + j1] = a1[i] + b1;
    if (tid < 128)
#pragma unroll
      for (int i = 0; i < 8; ++i) mbo[(size_t)(bn0 + i) * 384 + j2] = a2[i] + b2;
  }
}

// ---------------------------------------------------------------------------
// K1: P = bf16(query @ W_gen + b_gen)   (1216 x 53248, K=256)
// R4-verbatim (verified): Bq LDS stage for B-fragments, LDS reused as A
// double-buffer staged via global_load_lds (pre-swizzled source), one
// barrier per rc iteration.
// ---------------------------------------------------------------------------
__global__ __launch_bounds__(256) void k_params(const bf16* __restrict__ qbf,
                                                const float* __restrict__ Wg,
                                                const float* __restrict__ bg,
                                                bf16* __restrict__ P) {
  __shared__ __align__(16) bf16 lds[256 * 132];   // 67.6 KB: Bq, then A dbuf

  const int tid  = threadIdx.x;
  const int col0 = blockIdx.x * 128;
  const int wave = tid >> 6, lane = tid & 63;
  const int l15  = lane & 15, lhi = lane >> 4;

  // ---- Phase 1: B fragments ----
  for (int i = 0; i < 32; ++i) {
    int idx4 = i * 256 + tid;           // 8192 float4 = 256 q x 32 j4
    int q = idx4 >> 5, j4 = idx4 & 31;
    float4 v = *(const float4*)&Wg[(size_t)q * NCOL + col0 + j4 * 4];
    b16x4 w;
    w[0] = (bf16)v.x; w[1] = (bf16)v.y; w[2] = (bf16)v.z; w[3] = (bf16)v.w;
    *(b16x4*)&lds[q * 132 + j4 * 4] = w;
  }
  __syncthreads();

  b16x8 bfrag[2][8];
  float bcol[2];
#pragma unroll
  for (int nt = 0; nt < 2; ++nt) {
    int col = wave * 32 + nt * 16 + l15;
#pragma unroll
    for (int kk = 0; kk < 8; ++kk)
#pragma unroll
      for (int j = 0; j < 8; ++j)
        bfrag[nt][kk][j] = lds[(kk * 32 + lhi * 8 + j) * 132 + col];
    bcol[nt] = bg[col0 + col];
  }
  __syncthreads();   // Bq dead; LDS becomes A double-buffer

  // ---- Phase 2: K-loop over 19 row-tiles ----
  const char* qb = (const char*)qbf;
#define STAGE_A(b, rc)                                                         \
  {                                                                            \
    const char* s0 = qb + (size_t)(rc) * 64 * 512;                             \
    _Pragma("unroll")                                                          \
    for (int i = 0; i < 8; ++i) {                                              \
      int c = i * 256 + wave * 64 + lane;                                      \
      int r = c >> 5;                                                          \
      int boff = ((c & 31) << 4) ^ ((r & 7) << 4);                             \
      const void* src = (const void*)(s0 + r * 512 + boff);                    \
      bf16* dst = &lds[(b) * 16384 + (size_t)(i * 256 + wave * 64) * 8];       \
      __builtin_amdgcn_global_load_lds(                                        \
          (const __attribute__((address_space(1))) void*)src,                  \
          (__attribute__((address_space(3))) void*)dst, 16, 0, 0);             \
    }                                                                          \
  }

  STAGE_A(0, 0);
  __syncthreads();   // drain prologue staging

  for (int rc = 0; rc < 19; ++rc) {
    int cur = rc & 1;
    if (rc + 1 < 19) STAGE_A(cur ^ 1, rc + 1);   // prefetch flies under compute

    const bf16* At = &lds[cur * 16384];
    int r0 = rc * 64;
    f32x4 acc[4][2] = {};
#pragma unroll
    for (int kk = 0; kk < 8; ++kk)
#pragma unroll
      for (int mt = 0; mt < 4; ++mt) {
        int row = mt * 16 + l15;
        int coff = (kk * 32 + lhi * 8) ^ ((l15 & 7) << 3);
        b16x8 af = *(const b16x8*)&At[row * 256 + coff];
        acc[mt][0] = __builtin_amdgcn_mfma_f32_16x16x32_bf16(af, bfrag[0][kk], acc[mt][0], 0, 0, 0);
        acc[mt][1] = __builtin_amdgcn_mfma_f32_16x16x32_bf16(af, bfrag[1][kk], acc[mt][1], 0, 0, 0);
      }
#pragma unroll
    for (int mt = 0; mt < 4; ++mt) {
      int rbase = r0 + mt * 16 + lhi * 4;
#pragma unroll
      for (int nt = 0; nt < 2; ++nt) {
        size_t cg = (size_t)col0 + wave * 32 + nt * 16 + l15;
        bf16* pp = &P[(size_t)rbase * NCOL + cg];
#pragma unroll
        for (int r = 0; r < 4; ++r)
          pp[(size_t)r * NCOL] = (bf16)(acc[mt][nt][r] + bcol[nt]);
      }
    }
    __syncthreads();   // prefetch complete + buffer safe to overwrite
  }
#undef STAGE_A
}

// ---------------------------------------------------------------------------
// K2: per-(bn,g) cascade mix. R4-verbatim (verified): M/S fragments direct
// from P; S prefetched to registers BEFORE the barrier; x direct from HBM;
// h1T only in LDS (37.9 KB).
// ---------------------------------------------------------------------------
__global__ __launch_bounds__(256, 3) void k_mix(const float* __restrict__ x,
                                                const bf16* __restrict__ P,
                                                const float* __restrict__ mb,
                                                bf16* __restrict__ H) {
  __shared__ __align__(16) bf16 h1T[64 * 296];   // [d][p], 37.9 KB

  const int blk = blockIdx.x;
  const int bn = blk >> 2, g = blk & 3;
  const int tid = threadIdx.x;
  const int wave = tid >> 6, lane = tid & 63;
  const int l15 = lane & 15, lhi = lane >> 4;

  const size_t pb = (size_t)bn * NCOL + g * 13312;
  const float* mbp = mb + (size_t)bn * 384 + g * 96;

  // M fragments (B-operand [k=c][n=d]) direct from P, scalar gather
  b16x8 mfrag[4][2];
  float mbv[4];
#pragma unroll
  for (int nt = 0; nt < 4; ++nt) {
    int d = nt * 16 + l15;
    mbv[nt] = mbp[d];
#pragma unroll
    for (int kk = 0; kk < 2; ++kk) {
      const bf16* mp = &P[pb + (size_t)(kk * 32 + lhi * 8) * 64 + d];
#pragma unroll
      for (int j = 0; j < 8; ++j) mfrag[nt][kk][j] = mp[(size_t)j * 64];
    }
  }

  // S fragments + S_b prefetched now (independent of h1) — MFMA2 phase
  // then runs entirely from registers + LDS.
  const int mt2 = wave >> 1;
  const int ntb = (wave & 1) * 2;
  const bf16* Sp = &P[pb + 4096];
  b16x8 sfrag[9];
#pragma unroll
  for (int kk = 0; kk < 9; ++kk)
    sfrag[kk] = *(const b16x8*)&Sp[(size_t)(mt2 * 16 + l15) * 288 + kk * 32 + lhi * 8];
  float sbv[4];
#pragma unroll
  for (int r = 0; r < 4; ++r) sbv[r] = mbp[64 + mt2 * 16 + lhi * 4 + r];

  // MFMA1: h1 = relu(x @ M * 0.125 + M_b), A = x streamed from HBM
  const float* xp0 = &x[((size_t)bn * 4 + g) * 18432];
#pragma unroll
  for (int m0 = 0; m0 < 5; ++m0) {
    int mt = wave + m0 * 4;
    if (mt < 18) {
      f32x4 acc[4] = {};
#pragma unroll
      for (int kk = 0; kk < 2; ++kk) {
        const float* xp = xp0 + (mt * 16 + l15) * 64 + kk * 32 + lhi * 8;
        float4 a0 = *(const float4*)xp;
        float4 a1 = *(const float4*)(xp + 4);
        b16x8 af;
        af[0] = (bf16)a0.x; af[1] = (bf16)a0.y; af[2] = (bf16)a0.z; af[3] = (bf16)a0.w;
        af[4] = (bf16)a1.x; af[5] = (bf16)a1.y; af[6] = (bf16)a1.z; af[7] = (bf16)a1.w;
#pragma unroll
        for (int nt = 0; nt < 4; ++nt)
          acc[nt] = __builtin_amdgcn_mfma_f32_16x16x32_bf16(af, mfrag[nt][kk], acc[nt], 0, 0, 0);
      }
#pragma unroll
      for (int nt = 0; nt < 4; ++nt) {
        int d = nt * 16 + l15;
        b16x4 hv;
#pragma unroll
        for (int r = 0; r < 4; ++r) {
          float v = acc[nt][r] * 0.125f + mbv[nt];   // /TEMPER then +M_b
          hv[r] = (bf16)(v > 0.f ? v : 0.f);
        }
        *(b16x4*)&h1T[d * 296 + mt * 16 + lhi * 4] = hv;
      }
    }
  }
  __syncthreads();

  // MFMA2: h2 = relu(S @ h1 + S_b), S already in registers
  f32x4 acc2[2] = {};
#pragma unroll
  for (int kk = 0; kk < 9; ++kk) {
#pragma unroll
    for (int t = 0; t < 2; ++t) {
      b16x8 bfv = *(const b16x8*)&h1T[((ntb + t) * 16 + l15) * 296 + kk * 32 + lhi * 8];
      acc2[t] = __builtin_amdgcn_mfma_f32_16x16x32_bf16(sfrag[kk], bfv, acc2[t], 0, 0, 0);
    }
  }
  bf16* Hp = H + (size_t)bn * 8192 + g * 64;       // H[bn][o][g][c]
#pragma unroll
  for (int r = 0; r < 4; ++r) {
    int o = mt2 * 16 + lhi * 4 + r;
#pragma unroll
    for (int t = 0; t < 2; ++t) {
      float v = acc2[t][r] + sbv[r];
      Hp[o * 256 + (ntb + t) * 16 + l15] = (bf16)(v > 0.f ? v : 0.f);
    }
  }
}

// ---------------------------------------------------------------------------
// K3: part[kz] = H[:, kz*512:+512] @ W_vT^T   (split-K=16, fp32 partials)
// LDS-free, sync-free: A from H (L3), B from WvT (L3), register fragments.
// ---------------------------------------------------------------------------
__global__ __launch_bounds__(256) void k_out(const bf16* __restrict__ H,
                                             const bf16* __restrict__ WvT,
                                             float* __restrict__ part) {
  const int tid = threadIdx.x;
  const int wave = tid >> 6, lane = tid & 63;
  const int l15 = lane & 15, lhi = lane >> 4;
  const int r0 = blockIdx.x * 64;
  const int k0 = blockIdx.y * 512;

  f32x4 acc[4][4] = {};
  for (int it = 0; it < 8; ++it) {
    int kb = k0 + it * 64;
    b16x8 bfv[2][4], afv[2][4];
#pragma unroll
    for (int kk = 0; kk < 2; ++kk)
#pragma unroll
      for (int nt = 0; nt < 4; ++nt)
        bfv[kk][nt] = *(const b16x8*)&WvT[(size_t)(wave * 64 + nt * 16 + l15) * 8192 + kb + kk * 32 + lhi * 8];
#pragma unroll
    for (int kk = 0; kk < 2; ++kk)
#pragma unroll
      for (int mt = 0; mt < 4; ++mt)
        afv[kk][mt] = *(const b16x8*)&H[(size_t)(r0 + mt * 16 + l15) * 8192 + kb + kk * 32 + lhi * 8];
#pragma unroll
    for (int kk = 0; kk < 2; ++kk)
#pragma unroll
      for (int mt = 0; mt < 4; ++mt)
#pragma unroll
        for (int nt = 0; nt < 4; ++nt)
          acc[mt][nt] = __builtin_amdgcn_mfma_f32_16x16x32_bf16(afv[kk][mt], bfv[kk][nt], acc[mt][nt], 0, 0, 0);
  }
  const size_t pbase = (size_t)blockIdx.y * PROWS * 256;
#pragma unroll
  for (int mt = 0; mt < 4; ++mt)
#pragma unroll
    for (int nt = 0; nt < 4; ++nt) {
      int col = wave * 64 + nt * 16 + l15;
#pragma unroll
      for (int r = 0; r < 4; ++r) {
        int row = r0 + mt * 16 + lhi * 4 + r;
        part[pbase + (size_t)row * 256 + col] = acc[mt][nt][r];
      }
    }
}

// ---------------------------------------------------------------------------
// K4: out = LayerNorm(sum_kz part + b_v) * ln_g + ln_b   (one block per row)
// ---------------------------------------------------------------------------
__global__ __launch_bounds__(256) void k_ln(const float* __restrict__ part,
                                            const float* __restrict__ bv,
                                            const float* __restrict__ lng,
                                            const float* __restrict__ lnb,
                                            float* __restrict__ out) {
  __shared__ float red[8];
  const int row = blockIdx.x, c = threadIdx.x;
  const int wave = c >> 6, lane = c & 63;
  float v = bv[c];
  for (int kz = 0; kz < 16; ++kz)
    v += part[((size_t)kz * PROWS + row) * 256 + c];
  float s = v;
  for (int off = 32; off > 0; off >>= 1) s += __shfl_xor(s, off);
  if (lane == 0) red[wave] = s;
  __syncthreads();
  float mean = (red[0] + red[1] + red[2] + red[3]) * (1.0f / 256.0f);
  float d = v - mean;
  float q = d * d;
  for (int off = 32; off > 0; off >>= 1) q += __shfl_xor(q, off);
  if (lane == 0) red[4 + wave] = q;
  __syncthreads();
  float var = (red[4] + red[5] + red[6] + red[7]) * (1.0f / 256.0f);
  out[(size_t)row * 256 + c] = d * rsqrtf(var + 1e-5f) * lng[c] + lnb[c];
}

// ---------------------------------------------------------------------------
extern "C" void kernel_launch(void* const* d_in, const int* in_sizes, int n_in,
                              void* d_out, int out_size, void* d_ws, size_t ws_size,
                              hipStream_t stream) {
  const float* x   = (const float*)d_in[0];
  const float* qry = (const float*)d_in[1];
  const float* Wg  = (const float*)d_in[2];
  const float* bg  = (const float*)d_in[3];
  const float* Wb  = (const float*)d_in[4];
  const float* bb  = (const float*)d_in[5];
  const float* Wv  = (const float*)d_in[6];
  const float* bv  = (const float*)d_in[7];
  const float* lng = (const float*)d_in[8];
  const float* lnb = (const float*)d_in[9];
  float* out = (float*)d_out;

  // ws layout (bytes):
  char* ws = (char*)d_ws;
  bf16*  P    = (bf16*) (ws + 0);           // params bf16: 1216*53248*2 = 129,499,136
  bf16*  H    = (bf16*) (ws + 129499136);   // h2 bf16:     1216*8192*2  = 19,922,944
  float* mbw  = (float*)(ws + 149422080);   // mix bias:    1200*384*4   = 1,843,200
  bf16*  WvT  = (bf16*) (ws + 151265280);   // W_v^T bf16:  256*8192*2   = 4,194,304
  float* part = (float*)(ws + 155459584);   // splitK:      16*1216*256*4 = 19,922,944
  bf16*  qbf  = (bf16*) (ws + 155459584);   // aliased over part (dead before k_out)

  k_pre<<<814, 256, 0, stream>>>(Wv, WvT, qry, qbf, Wb, bb, mbw);
  k_params<<<416, 256, 0, stream>>>(qbf, Wg, bg, P);
  k_mix<<<4800, 256, 0, stream>>>(x, P, mbw, H);
  k_out<<<dim3(19, 16), 256, 0, stream>>>(H, WvT, part);
  k_ln<<<1200, 256, 0, stream>>>(part, bv, lng, lnb, out);
}